// Round 9
// baseline (944.078 us; speedup 1.0000x reference)
//
#include <hip/hip_runtime.h>
#include <cstdint>
#include <cstddef>

#define NN 25000        // nodes
#define NE 100000       // edges
#define NEP 125000      // edges + self loops
#define NG 512          // graphs
#define HEADS 10
#define FXD 78
#define HF 780          // HEADS*FXD
#define SEQ 1000
#define EMBD 128
#define NFILT 32
#define VOCAB 26
#define CONVO 121       // EMB-8+1
#define KCONV 8
#define VK (VOCAB*KCONV)     // 208
#define AROW (NFILT*VK)      // 6656
#define KP_GAT 80            // 78 padded to mult of 16
#define KP_GCN 784           // 780 padded to mult of 16

typedef unsigned short u16;
typedef short bf16x8 __attribute__((ext_vector_type(8)));
typedef float f32x4 __attribute__((ext_vector_type(4)));

// round-to-nearest-even bf16 split: v ~= hi + lo
__device__ inline void bsplit(float v, u16& h, u16& l) {
    unsigned u = __builtin_bit_cast(unsigned, v);
    unsigned hb = (u + 0x7fffu + ((u >> 16) & 1u)) >> 16;
    float fh = __builtin_bit_cast(float, hb << 16);
    float r = v - fh;
    unsigned u2 = __builtin_bit_cast(unsigned, r);
    unsigned lb = (u2 + 0x7fffu + ((u2 >> 16) & 1u)) >> 16;
    h = (u16)hb; l = (u16)lb;
}

// ---------------------------------------------------------------- CSR build
__global__ void k_deg(const int* __restrict__ ei, int* __restrict__ deg) {
    int e = blockIdx.x * blockDim.x + threadIdx.x;
    if (e >= NEP) return;
    int d = (e < NE) ? ei[NE + e] : (e - NE);
    atomicAdd(&deg[d], 1);
}

__global__ __launch_bounds__(1024) void k_scan(const int* __restrict__ deg, int* __restrict__ off) {
    __shared__ int tsum[1024];
    const int tid = threadIdx.x;
    const int base = tid * 25;
    int s = 0;
    for (int i = 0; i < 25; ++i) { int g = base + i; if (g < NN) s += deg[g]; }
    tsum[tid] = s;
    __syncthreads();
    for (int o = 1; o < 1024; o <<= 1) {
        int v = (tid >= o) ? tsum[tid - o] : 0;
        __syncthreads();
        tsum[tid] += v;
        __syncthreads();
    }
    int run = tid ? tsum[tid - 1] : 0;
    for (int i = 0; i < 25; ++i) {
        int g = base + i;
        if (g < NN) { off[g] = run; run += deg[g]; }
    }
    if (tid == 1023) off[NN] = tsum[1023];
}

__global__ void k_fill(const int* __restrict__ ei, const int* __restrict__ off,
                       int* __restrict__ fill, int* __restrict__ csrc) {
    int e = blockIdx.x * blockDim.x + threadIdx.x;
    if (e >= NEP) return;
    int s = (e < NE) ? ei[e]      : (e - NE);
    int d = (e < NE) ? ei[NE + e] : (e - NE);
    int pos = off[d] + atomicAdd(&fill[d], 1);
    csrc[pos] = s;
}

__global__ void k_dinv(const int* __restrict__ deg, float* __restrict__ dinv) {
    int n = blockIdx.x * blockDim.x + threadIdx.x;
    if (n >= NN) return;
    int dg = deg[n];
    dinv[n] = dg > 0 ? 1.0f / sqrtf((float)dg) : 0.0f;
}

// ---------------------------------------------------------------- split / transpose-split
__global__ void k_split(const float* __restrict__ src, u16* __restrict__ hi,
                        u16* __restrict__ lo, int M, int Ks, int Kp) {
    int half = Kp >> 1;
    int i = blockIdx.x * blockDim.x + threadIdx.x;
    if (i >= M * half) return;
    int m = i / half, kp = (i - m * half) * 2;
    const float* row = src + (size_t)m * Ks;
    float v0 = 0.f, v1 = 0.f;
    if (kp + 1 < Ks) { float2 t = *(const float2*)(row + kp); v0 = t.x; v1 = t.y; }
    else if (kp < Ks) v0 = row[kp];
    u16 h0, l0, h1, l1;
    bsplit(v0, h0, l0); bsplit(v1, h1, l1);
    size_t o = (size_t)m * Kp + kp;
    *(unsigned*)(hi + o) = (unsigned)h0 | ((unsigned)h1 << 16);
    *(unsigned*)(lo + o) = (unsigned)l0 | ((unsigned)l1 << 16);
}

// Th/Tl[N][Kp] <- W[K][N] transposed, zero-padded k in [K,Kp)
__global__ __launch_bounds__(256) void k_tsplit(const float* __restrict__ W,
                                                u16* __restrict__ Th, u16* __restrict__ Tl,
                                                int K, int N, int Kp) {
    __shared__ float tile[32][33];
    int n0 = blockIdx.x * 32, k0 = blockIdx.y * 32;
    int tx = threadIdx.x & 31, ty = threadIdx.x >> 5;   // 32x8
#pragma unroll
    for (int r = 0; r < 4; ++r) {
        int k = k0 + ty + r * 8, n = n0 + tx;
        tile[ty + r * 8][tx] = (k < K && n < N) ? W[(size_t)k * N + n] : 0.f;
    }
    __syncthreads();
#pragma unroll
    for (int r = 0; r < 4; ++r) {
        int nl = ty + r * 8, n = n0 + nl, k = k0 + tx;
        if (n < N && k < Kp) {
            u16 h, l;
            bsplit(tile[tx][nl], h, l);
            Th[(size_t)n * Kp + k] = h;
            Tl[(size_t)n * Kp + k] = l;
        }
    }
}

// ---------------------------------------------------------------- split-bf16 MFMA GEMM
// Grid: (col tiles, row tiles) — col fastest so co-resident blocks share the A row panel (L2 reuse).
__global__ __launch_bounds__(256, 2) void k_mfma_gemm(
    const u16* __restrict__ Ah, const u16* __restrict__ Al,
    const u16* __restrict__ Bh, const u16* __restrict__ Bl,
    const float* __restrict__ bias, float* __restrict__ C,
    int M, int N, int Kp, int ldc, int relu) {
    __shared__ __align__(16) u16 sAh[128][40];
    __shared__ __align__(16) u16 sAl[128][40];
    __shared__ __align__(16) u16 sBh[128][40];
    __shared__ __align__(16) u16 sBl[128][40];
    const int tid = threadIdx.x;
    const int bm = blockIdx.y * 128, bn = blockIdx.x * 128;   // swapped: x=col, y=row
    const int lane = tid & 63, w = tid >> 6;
    const int wm = (w >> 1) * 64, wn = (w & 1) * 64;
    const int r16 = lane & 15, kb = (lane >> 4) * 8;
    const int srow = tid >> 1, shalf = tid & 1;
    const int arow = bm + srow, brow = bn + srow;
    const size_t aoff = (size_t)arow * Kp + shalf * 16;
    const size_t boff = (size_t)brow * Kp + shalf * 16;
    const int nsteps = (Kp + 31) / 32;

    uint4 pva[2], pvl[2], pvb[2], pwb[2];
    auto gload = [&](int s) {
        int k0 = s * 32;
        int kc = k0 + shalf * 16;
        bool kok = (kc + 16 <= Kp);
        uint4 z = {0, 0, 0, 0};
        pva[0] = pva[1] = pvl[0] = pvl[1] = z;
        pvb[0] = pvb[1] = pwb[0] = pwb[1] = z;
        if (kok && arow < M) {
            const uint4* p = (const uint4*)(Ah + aoff + k0);
            pva[0] = p[0]; pva[1] = p[1];
            const uint4* q = (const uint4*)(Al + aoff + k0);
            pvl[0] = q[0]; pvl[1] = q[1];
        }
        if (kok && brow < N) {
            const uint4* p = (const uint4*)(Bh + boff + k0);
            pvb[0] = p[0]; pvb[1] = p[1];
            const uint4* q = (const uint4*)(Bl + boff + k0);
            pwb[0] = q[0]; pwb[1] = q[1];
        }
    };

    f32x4 acc[4][4] = {};
    gload(0);
    for (int s = 0; s < nsteps; ++s) {
        __syncthreads();
        {
            const int kk = shalf * 16;
            *(uint4*)&sAh[srow][kk] = pva[0]; *(uint4*)&sAh[srow][kk + 8] = pva[1];
            *(uint4*)&sAl[srow][kk] = pvl[0]; *(uint4*)&sAl[srow][kk + 8] = pvl[1];
            *(uint4*)&sBh[srow][kk] = pvb[0]; *(uint4*)&sBh[srow][kk + 8] = pvb[1];
            *(uint4*)&sBl[srow][kk] = pwb[0]; *(uint4*)&sBl[srow][kk + 8] = pwb[1];
        }
        __syncthreads();
        if (s + 1 < nsteps) gload(s + 1);
        bf16x8 fah[4], fal[4], fbh[4], fbl[4];
#pragma unroll
        for (int i = 0; i < 4; ++i) {
            fah[i] = *(const bf16x8*)&sAh[wm + i * 16 + r16][kb];
            fal[i] = *(const bf16x8*)&sAl[wm + i * 16 + r16][kb];
            fbh[i] = *(const bf16x8*)&sBh[wn + i * 16 + r16][kb];
            fbl[i] = *(const bf16x8*)&sBl[wn + i * 16 + r16][kb];
        }
#pragma unroll
        for (int i = 0; i < 4; ++i)
#pragma unroll
            for (int j = 0; j < 4; ++j) {
                acc[i][j] = __builtin_amdgcn_mfma_f32_16x16x32_bf16(fal[i], fbh[j], acc[i][j], 0, 0, 0);
                acc[i][j] = __builtin_amdgcn_mfma_f32_16x16x32_bf16(fah[i], fbl[j], acc[i][j], 0, 0, 0);
                acc[i][j] = __builtin_amdgcn_mfma_f32_16x16x32_bf16(fah[i], fbh[j], acc[i][j], 0, 0, 0);
            }
    }
    const int rbase = (lane >> 4) * 4;
#pragma unroll
    for (int j = 0; j < 4; ++j) {
        int col = bn + wn + j * 16 + r16;
        if (col >= N) continue;
        float bb = bias ? bias[col] : 0.f;
#pragma unroll
        for (int i = 0; i < 4; ++i) {
#pragma unroll
            for (int r = 0; r < 4; ++r) {
                int row = bm + wm + i * 16 + rbase + r;
                if (row < M) {
                    float v = acc[i][j][r] + bb;
                    if (relu) v = fmaxf(v, 0.f);
                    C[(size_t)row * ldc + col] = v;
                }
            }
        }
    }
}

// ---------------------------------------------------------------- GAT attention
__global__ void k_att(const float* __restrict__ h, const float* __restrict__ wsrc,
                      const float* __restrict__ wdst, float* __restrict__ asrc,
                      float* __restrict__ adst) {
    int node = blockIdx.x * 4 + (threadIdx.x >> 6);
    int lane = threadIdx.x & 63;
    if (node >= NN) return;
    const float* row = h + (size_t)node * HF;
    for (int hh = 0; hh < HEADS; ++hh) {
        float ps = 0.f, pd = 0.f;
        for (int f = lane; f < FXD; f += 64) {
            float v = row[hh * FXD + f];
            ps += v * wsrc[hh * FXD + f];
            pd += v * wdst[hh * FXD + f];
        }
        for (int o = 32; o > 0; o >>= 1) {
            ps += __shfl_down(ps, o);
            pd += __shfl_down(pd, o);
        }
        if (lane == 0) {
            asrc[node * HEADS + hh] = ps;
            adst[node * HEADS + hh] = pd;
        }
    }
}

__global__ void k_mden(const int* __restrict__ off, const int* __restrict__ csrc,
                       const float* __restrict__ asrc, const float* __restrict__ adst,
                       float* __restrict__ mbuf, float* __restrict__ dbuf) {
    int idx = blockIdx.x * blockDim.x + threadIdx.x;
    if (idx >= NN * HEADS) return;
    int d = idx / HEADS, hh = idx % HEADS;
    int s0 = off[d], s1 = off[d + 1];
    float ad = adst[idx];
    float m = -1e30f;
    for (int p = s0; p < s1; ++p) {
        float v = asrc[csrc[p] * HEADS + hh] + ad;
        v = v > 0.f ? v : 0.2f * v;
        m = fmaxf(m, v);
    }
    float den = 0.f;
    for (int p = s0; p < s1; ++p) {
        float v = asrc[csrc[p] * HEADS + hh] + ad;
        v = v > 0.f ? v : 0.2f * v;
        den += expf(v - m);
    }
    mbuf[idx] = m;
    dbuf[idx] = den;
}

// block per dst node: alpha inline, float4 feature MACs
__global__ __launch_bounds__(256) void k_gat_feat(
    const int* __restrict__ off, const int* __restrict__ csrc,
    const float* __restrict__ asrc, const float* __restrict__ adst,
    const float* __restrict__ mbuf, const float* __restrict__ dbuf,
    const float* __restrict__ h, const float* __restrict__ gat_b,
    float* __restrict__ x1) {
    __shared__ float lal[64 * HEADS];
    __shared__ int lsrc[64];
    __shared__ float s_ad[HEADS], s_m[HEADS], s_rd[HEADS];
    const int d = blockIdx.x, tid = threadIdx.x;
    if (tid < HEADS) {
        s_ad[tid] = adst[d * HEADS + tid];
        s_m[tid]  = mbuf[d * HEADS + tid];
        s_rd[tid] = 1.0f / (dbuf[d * HEADS + tid] + 1e-16f);
    }
    const int s0 = off[d], s1 = off[d + 1];
    int hj[4];
#pragma unroll
    for (int j = 0; j < 4; ++j) hj[j] = (tid < 195) ? (tid * 4 + j) / FXD : 0;
    float4 acc = {0.f, 0.f, 0.f, 0.f};
    for (int c0 = s0; c0 < s1; c0 += 64) {
        int cs = min(64, s1 - c0);
        __syncthreads();
        for (int i = tid; i < cs; i += 256) lsrc[i] = csrc[c0 + i];
        __syncthreads();
        for (int i = tid; i < cs * HEADS; i += 256) {
            int e = i / HEADS, hh = i - e * HEADS;
            float v = asrc[lsrc[e] * HEADS + hh] + s_ad[hh];
            v = v > 0.f ? v : 0.2f * v;
            lal[i] = __expf(v - s_m[hh]) * s_rd[hh];
        }
        __syncthreads();
        if (tid < 195) {
            for (int e = 0; e < cs; ++e) {
                const float4 hv = reinterpret_cast<const float4*>(h + (size_t)lsrc[e] * HF)[tid];
                const float* wv = &lal[e * HEADS];
                acc.x += wv[hj[0]] * hv.x;
                acc.y += wv[hj[1]] * hv.y;
                acc.z += wv[hj[2]] * hv.z;
                acc.w += wv[hj[3]] * hv.w;
            }
        }
    }
    if (tid < 195) {
        float4 b = reinterpret_cast<const float4*>(gat_b)[tid];
        float4 o;
        o.x = fmaxf(acc.x + b.x, 0.f);
        o.y = fmaxf(acc.y + b.y, 0.f);
        o.z = fmaxf(acc.z + b.z, 0.f);
        o.w = fmaxf(acc.w + b.w, 0.f);
        reinterpret_cast<float4*>(x1 + (size_t)d * HF)[tid] = o;
    }
}

// block per dst node: y = sum_e dinv[s]*dinv[d]*x1[s,:], bf16-split inline
__global__ __launch_bounds__(256) void k_gcn_agg(
    const int* __restrict__ off, const int* __restrict__ csrc,
    const float* __restrict__ dinv, const float* __restrict__ x1,
    u16* __restrict__ yAh, u16* __restrict__ yAl) {
    __shared__ float lno[256];
    __shared__ int lsrc[256];
    const int d = blockIdx.x, tid = threadIdx.x;
    const int s0 = off[d], s1 = off[d + 1];
    const float dd = dinv[d];
    float4 acc = {0.f, 0.f, 0.f, 0.f};
    for (int c0 = s0; c0 < s1; c0 += 256) {
        int cs = min(256, s1 - c0);
        __syncthreads();
        for (int i = tid; i < cs; i += 256) {
            int s = csrc[c0 + i];
            lsrc[i] = s;
            lno[i] = dinv[s] * dd;
        }
        __syncthreads();
        if (tid < 195) {
            for (int e = 0; e < cs; ++e) {
                const float4 v = reinterpret_cast<const float4*>(x1 + (size_t)lsrc[e] * HF)[tid];
                float wv = lno[e];
                acc.x += wv * v.x; acc.y += wv * v.y; acc.z += wv * v.z; acc.w += wv * v.w;
            }
        }
    }
    if (tid < 195) {
        ushort4 hv, lv;
        bsplit(acc.x, hv.x, lv.x); bsplit(acc.y, hv.y, lv.y);
        bsplit(acc.z, hv.z, lv.z); bsplit(acc.w, hv.w, lv.w);
        *reinterpret_cast<ushort4*>(yAh + (size_t)d * KP_GCN + tid * 4) = hv;
        *reinterpret_cast<ushort4*>(yAl + (size_t)d * KP_GCN + tid * 4) = lv;
    } else if (tid == 195) {
        ushort4 z = {0, 0, 0, 0};
        *reinterpret_cast<ushort4*>(yAh + (size_t)d * KP_GCN + 780) = z;
        *reinterpret_cast<ushort4*>(yAl + (size_t)d * KP_GCN + 780) = z;
    }
}

// ---------------------------------------------------------------- pooling
__global__ void k_gstart(const int* __restrict__ batch, int* __restrict__ gstart) {
    int g = blockIdx.x * blockDim.x + threadIdx.x;
    if (g > NG) return;
    int lo = 0, hi = NN;
    while (lo < hi) {
        int mid = (lo + hi) >> 1;
        if (batch[mid] < g) lo = mid + 1; else hi = mid;
    }
    gstart[g] = lo;
}

__global__ __launch_bounds__(256) void k_pool(const int* __restrict__ gstart,
                                              const float* __restrict__ x2,
                                              float* __restrict__ pool) {
    const int g = blockIdx.x, tid = threadIdx.x;
    const int s0 = gstart[g], s1 = gstart[g + 1];
    if (tid >= 195) return;
    float4 mx = {0.f, 0.f, 0.f, 0.f};
    float4 sm = {0.f, 0.f, 0.f, 0.f};
    for (int n = s0; n < s1; ++n) {
        float4 v = reinterpret_cast<const float4*>(x2 + (size_t)n * HF)[tid];
        sm.x += v.x; sm.y += v.y; sm.z += v.z; sm.w += v.w;
        mx.x = fmaxf(mx.x, v.x); mx.y = fmaxf(mx.y, v.y);
        mx.z = fmaxf(mx.z, v.z); mx.w = fmaxf(mx.w, v.w);
    }
    float inv = 1.0f / (float)max(s1 - s0, 1);
    sm.x *= inv; sm.y *= inv; sm.z *= inv; sm.w *= inv;
    reinterpret_cast<float4*>(pool + (size_t)g * (2 * HF))[tid] = mx;
    reinterpret_cast<float4*>(pool + (size_t)g * (2 * HF) + HF)[tid] = sm;
}

// ---------------------------------------------------------------- split-K head GEMMs
__global__ __launch_bounds__(256) void k_gemm_sk(
    const float* __restrict__ A, const float* __restrict__ B,
    float* __restrict__ P, int M, int N, int K, int KS) {
    __shared__ __align__(16) float As[16][64];
    __shared__ __align__(16) float Bs[16][64];
    const int bm = blockIdx.x * 64, bn = blockIdx.y * 64;
    const int s = blockIdx.z;
    const int k0 = s * KS, k1 = min(k0 + KS, K);
    const int tid = threadIdx.x;
    const int tx = tid & 15, ty = tid >> 4;
    const int arow = tid >> 2, akq = (tid & 3) * 4;
    const int bkk = tid >> 4, bc4 = (tid & 15) * 4;
    float acc[4][4] = {};
    for (int kt = k0; kt < k1; kt += 16) {
        __syncthreads();
        {
            int gk = kt + akq;
            float4 v = {0.f, 0.f, 0.f, 0.f};
            if (gk + 4 <= k1) v = *reinterpret_cast<const float4*>(&A[(size_t)(bm + arow) * K + gk]);
            As[akq + 0][arow] = v.x; As[akq + 1][arow] = v.y;
            As[akq + 2][arow] = v.z; As[akq + 3][arow] = v.w;
            int kk = kt + bkk;
            float4 wv = {0.f, 0.f, 0.f, 0.f};
            if (kk < k1) wv = *reinterpret_cast<const float4*>(&B[(size_t)kk * N + bn + bc4]);
            *reinterpret_cast<float4*>(&Bs[bkk][bc4]) = wv;
        }
        __syncthreads();
#pragma unroll
        for (int kk = 0; kk < 16; ++kk) {
            float4 a = *reinterpret_cast<const float4*>(&As[kk][ty * 4]);
            float4 b = *reinterpret_cast<const float4*>(&Bs[kk][tx * 4]);
            float av[4] = {a.x, a.y, a.z, a.w};
            float bv[4] = {b.x, b.y, b.z, b.w};
#pragma unroll
            for (int i = 0; i < 4; ++i)
#pragma unroll
                for (int j = 0; j < 4; ++j) acc[i][j] += av[i] * bv[j];
        }
    }
    float* Pr = P + (size_t)s * M * N;
#pragma unroll
    for (int i = 0; i < 4; ++i) {
        int row = bm + ty * 4 + i;
        float4 v = {acc[i][0], acc[i][1], acc[i][2], acc[i][3]};
        *reinterpret_cast<float4*>(&Pr[(size_t)row * N + bn + tx * 4]) = v;
    }
}

__global__ void k_reduce(const float* __restrict__ P, const float* __restrict__ bias,
                         float* __restrict__ C, int M, int N, int S, int ldc, int relu) {
    int i = blockIdx.x * blockDim.x + threadIdx.x;
    int nq = N >> 2;
    if (i >= M * nq) return;
    int m = i / nq, c4 = (i - m * nq) * 4;
    const float4* p = reinterpret_cast<const float4*>(P) + i;
    size_t stride4 = (size_t)M * nq;
    float4 a = p[0];
    for (int s = 1; s < S; ++s) {
        float4 v = p[(size_t)s * stride4];
        a.x += v.x; a.y += v.y; a.z += v.z; a.w += v.w;
    }
    float4 b = *reinterpret_cast<const float4*>(bias + c4);
    a.x += b.x; a.y += b.y; a.z += b.z; a.w += b.w;
    if (relu) {
        a.x = fmaxf(a.x, 0.f); a.y = fmaxf(a.y, 0.f);
        a.z = fmaxf(a.z, 0.f); a.w = fmaxf(a.w, 0.f);
    }
    *reinterpret_cast<float4*>(&C[(size_t)m * ldc + c4]) = a;
}

__global__ void k_gemv_out(const float* __restrict__ A, const float* __restrict__ w,
                           const float* __restrict__ b, float* __restrict__ out) {
    int m = blockIdx.x * 4 + (threadIdx.x >> 6);
    int lane = threadIdx.x & 63;
    if (m >= NG) return;
    const float* row = A + (size_t)m * 512;
    float p = 0.f;
#pragma unroll
    for (int t = 0; t < 8; ++t) p += row[lane + t * 64] * w[lane + t * 64];
    for (int o = 32; o > 0; o >>= 1) p += __shfl_down(p, o);
    if (lane == 0) out[m] = p + b[0];
}

// ---------------------------------------------------------------- conv branch
__global__ void k_bmat(const float* __restrict__ emb, float* __restrict__ Bm) {
    int b = blockIdx.x;          // 0..207
    int p = threadIdx.x;
    if (p >= CONVO) return;
    int v = b >> 3, k = b & 7;
    Bm[b * CONVO + p] = emb[v * EMBD + p + k];
}

__global__ __launch_bounds__(256) void k_Amat(const int* __restrict__ target,
                                              const float* __restrict__ convW,
                                              float* __restrict__ Am) {
    __shared__ int vcnt[VOCAB];
    __shared__ int vfill[VOCAB];
    __shared__ int voff[VOCAB + 1];
    __shared__ int vpos[SEQ];
    const int g = blockIdx.x, tid = threadIdx.x;
    if (tid < VOCAB) { vcnt[tid] = 0; vfill[tid] = 0; }
    __syncthreads();
    const int* tg = target + (size_t)g * SEQ;
    for (int s = tid; s < SEQ; s += 256) atomicAdd(&vcnt[tg[s]], 1);
    __syncthreads();
    if (tid == 0) {
        int r = 0;
        for (int v = 0; v < VOCAB; ++v) { voff[v] = r; r += vcnt[v]; }
        voff[VOCAB] = r;
    }
    __syncthreads();
    for (int s = tid; s < SEQ; s += 256) {
        int v = tg[s];
        vpos[voff[v] + atomicAdd(&vfill[v], 1)] = s;
    }
    __syncthreads();
    const int o = tid >> 3, k = tid & 7;
    const float* wrow = convW + (size_t)o * (SEQ * KCONV) + k;
    float* arow = Am + (size_t)g * AROW + o * VK + k;
    for (int v = 0; v < VOCAB; ++v) {
        float r = 0.f;
        int p1 = voff[v + 1];
        for (int p = voff[v]; p < p1; ++p) r += wrow[(size_t)vpos[p] * KCONV];
        arow[v * KCONV] = r;
    }
}

__global__ __launch_bounds__(128) void k_conv(const float* __restrict__ Am,
                                              const float* __restrict__ Bm,
                                              const float* __restrict__ convb,
                                              float* __restrict__ out) {
    __shared__ float As[AROW];
    const int g = blockIdx.x, tid = threadIdx.x;
    for (int i = tid; i < AROW; i += 128) As[i] = Am[(size_t)g * AROW + i];
    __syncthreads();
    if (tid >= CONVO) return;
    const int p = tid;
    float acc[NFILT] = {};
    for (int vk = 0; vk < VK; ++vk) {
        float b = Bm[vk * CONVO + p];
#pragma unroll
        for (int o = 0; o < NFILT; ++o) acc[o] += As[o * VK + vk] * b;
    }
#pragma unroll
    for (int o = 0; o < NFILT; ++o)
        out[(size_t)g * (NFILT * CONVO) + o * CONVO + p] = acc[o] + convb[o];
}

// ---------------------------------------------------------------- launch
extern "C" void kernel_launch(void* const* d_in, const int* in_sizes, int n_in,
                              void* d_out, int out_size, void* d_ws, size_t ws_size,
                              hipStream_t stream) {
    const float* x        = (const float*)d_in[0];
    const int*   ei       = (const int*)d_in[1];
    const int*   batch    = (const int*)d_in[2];
    const int*   target   = (const int*)d_in[3];
    const float* gat_W    = (const float*)d_in[4];
    const float* gat_as   = (const float*)d_in[5];
    const float* gat_ad   = (const float*)d_in[6];
    const float* gat_b    = (const float*)d_in[7];
    const float* gcn_W    = (const float*)d_in[8];
    const float* gcn_b    = (const float*)d_in[9];
    const float* fcg1_W   = (const float*)d_in[10];
    const float* fcg1_b   = (const float*)d_in[11];
    const float* fcg2_W   = (const float*)d_in[12];
    const float* fcg2_b   = (const float*)d_in[13];
    const float* emb      = (const float*)d_in[14];
    const float* conv_W   = (const float*)d_in[15];
    const float* conv_b   = (const float*)d_in[16];
    const float* fcxt_W   = (const float*)d_in[17];
    const float* fcxt_b   = (const float*)d_in[18];
    const float* fc1_W    = (const float*)d_in[19];
    const float* fc1_b    = (const float*)d_in[20];
    const float* fc2_W    = (const float*)d_in[21];
    const float* fc2_b    = (const float*)d_in[22];
    const float* out_W    = (const float*)d_in[23];
    const float* out_b    = (const float*)d_in[24];
    float* outp = (float*)d_out;

    // ---- workspace layout (float units) ----
    // R1: h -> {yAh,yAl} -> small arena.     R2: x1 -> x2.
    const size_t R1SZ = 19600000, R2SZ = 19600000;
    float* R1   = (float*)d_ws;
    float* R2   = R1 + R1SZ;
    float* xAf  = R2 + R2SZ;                          // 2,000,000 (xAh+xAl)
    float* gWf  = xAf + 2000000;                      // 64,000
    float* cWf  = gWf + 64000;                        // 612,000 (cWh+cWl)
    float* asrc = cWf + 612000;
    float* adst = asrc + (size_t)NN * HEADS;
    float* mbuf = adst + (size_t)NN * HEADS;
    float* dbuf = mbuf + (size_t)NN * HEADS;
    float* dinv = dbuf + (size_t)NN * HEADS;
    int* deg      = (int*)(dinv + NN);
    int* csr_off  = deg + NN;
    int* csr_fill = csr_off + (NN + 1);
    int* csr_src  = csr_fill + NN;
    int* gstart   = csr_src + NEP;

    u16* xAh = (u16*)xAf;             u16* xAl = xAh + (size_t)NN * KP_GAT;
    u16* gWh = (u16*)gWf;             u16* gWl = gWh + (size_t)HF * KP_GAT;
    u16* cWh = (u16*)cWf;             u16* cWl = cWh + (size_t)HF * KP_GCN;

    hipMemsetAsync(deg, 0, NN * sizeof(int), stream);
    hipMemsetAsync(csr_fill, 0, NN * sizeof(int), stream);

    // ---- GAT: h = x @ gat_W via split-bf16 MFMA ----
    k_split<<<(NN * (KP_GAT / 2) + 255) / 256, 256, 0, stream>>>(x, xAh, xAl, NN, FXD, KP_GAT);
    k_tsplit<<<dim3((HF + 31) / 32, (KP_GAT + 31) / 32), 256, 0, stream>>>(
        gat_W, gWh, gWl, FXD, HF, KP_GAT);
    k_tsplit<<<dim3((HF + 31) / 32, (KP_GCN + 31) / 32), 256, 0, stream>>>(
        gcn_W, cWh, cWl, HF, HF, KP_GCN);
    k_mfma_gemm<<<dim3((HF + 127) / 128, (NN + 127) / 128), 256, 0, stream>>>(
        xAh, xAl, gWh, gWl, nullptr, R1, NN, HF, KP_GAT, HF, 0);        // h -> R1

    k_att<<<(NN + 3) / 4, 256, 0, stream>>>(R1, gat_as, gat_ad, asrc, adst);
    k_deg<<<(NEP + 255) / 256, 256, 0, stream>>>(ei, deg);
    k_scan<<<1, 1024, 0, stream>>>(deg, csr_off);
    k_fill<<<(NEP + 255) / 256, 256, 0, stream>>>(ei, csr_off, csr_fill, csr_src);
    k_dinv<<<(NN + 255) / 256, 256, 0, stream>>>(deg, dinv);
    k_mden<<<(NN * HEADS + 255) / 256, 256, 0, stream>>>(csr_off, csr_src, asrc, adst, mbuf, dbuf);
    k_gat_feat<<<NN, 256, 0, stream>>>(csr_off, csr_src, asrc, adst, mbuf, dbuf,
                                       R1, gat_b, R2);                  // x1 -> R2 (h in R1 dead)

    // ---- GCN: aggregate + inline bf16-split (x1 in R2 -> yA in R1), then MFMA ----
    k_gcn_agg<<<NN, 256, 0, stream>>>(csr_off, csr_src, dinv, R2, (u16*)R1,
                                      (u16*)R1 + (size_t)NN * KP_GCN);
    k_mfma_gemm<<<dim3((HF + 127) / 128, (NN + 127) / 128), 256, 0, stream>>>(
        (u16*)R1, (u16*)R1 + (size_t)NN * KP_GCN, cWh, cWl, gcn_b, R2,
        NN, HF, KP_GCN, HF, 1);                                         // x2 -> R2 (x1 dead)

    // ---- pooling + graph MLP (arena in R1; yA dead after GCN GEMM) ----
    float* poolR = R1;
    float* xg1R  = poolR + (size_t)NG * 2 * HF;
    float* xcR   = xg1R + (size_t)NG * 1024;
    float* f1R   = xcR + (size_t)NG * 256;
    float* f2R   = f1R + (size_t)NG * 1024;
    float* AmatR = f2R + (size_t)NG * 512;
    float* BmatR = AmatR + (size_t)NG * AROW;
    float* convR = BmatR + (size_t)VK * CONVO;
    float* partR = convR + (size_t)NG * NFILT * CONVO;

    k_gstart<<<1, 1024, 0, stream>>>(batch, gstart);
    k_pool<<<NG, 256, 0, stream>>>(gstart, R2, poolR);
    k_gemm_sk<<<dim3(8, 16, 8), 256, 0, stream>>>(poolR, fcg1_W, partR, NG, 1024, 1560, 208);
    k_reduce<<<512, 256, 0, stream>>>(partR, fcg1_b, xg1R, NG, 1024, 8, 1024, 1);
    k_gemm_sk<<<dim3(8, 2, 16), 256, 0, stream>>>(xg1R, fcg2_W, partR, NG, 128, 1024, 64);
    k_reduce<<<64, 256, 0, stream>>>(partR, fcg2_b, xcR, NG, 128, 16, 256, 0);

    // ---- target CNN branch (vocab-factorized conv) ----
    k_bmat<<<VK, 128, 0, stream>>>(emb, BmatR);
    k_Amat<<<NG, 256, 0, stream>>>(target, conv_W, AmatR);
    k_conv<<<NG, 128, 0, stream>>>(AmatR, BmatR, conv_b, convR);
    k_gemm_sk<<<dim3(8, 2, 16), 256, 0, stream>>>(convR, fcxt_W, partR, NG, 128, 3872, 256);
    k_reduce<<<64, 256, 0, stream>>>(partR, fcxt_b, xcR + 128, NG, 128, 16, 256, 0);

    // ---- fusion head ----
    k_gemm_sk<<<dim3(8, 16, 4), 256, 0, stream>>>(xcR, fc1_W, partR, NG, 1024, 256, 64);
    k_reduce<<<512, 256, 0, stream>>>(partR, fc1_b, f1R, NG, 1024, 4, 1024, 1);
    k_gemm_sk<<<dim3(8, 8, 8), 256, 0, stream>>>(f1R, fc2_W, partR, NG, 512, 1024, 128);
    k_reduce<<<256, 256, 0, stream>>>(partR, fc2_b, f2R, NG, 512, 8, 512, 1);
    k_gemv_out<<<128, 256, 0, stream>>>(f2R, out_W, out_b, outp);
}

// Round 11
// 869.213 us; speedup vs baseline: 1.0861x; 1.0861x over previous
//
#include <hip/hip_runtime.h>
#include <cstdint>
#include <cstddef>

#define NN 25000        // nodes
#define NE 100000       // edges
#define NEP 125000      // edges + self loops
#define NG 512          // graphs
#define HEADS 10
#define FXD 78
#define HF 780          // HEADS*FXD
#define SEQ 1000
#define EMBD 128
#define NFILT 32
#define VOCAB 26
#define CONVO 121       // EMB-8+1
#define KCONV 8
#define VK (VOCAB*KCONV)     // 208
#define AROW (NFILT*VK)      // 6656
#define KP_GAT 80            // 78 padded to mult of 16
#define KP_GCN 784           // 780 padded to mult of 16

typedef unsigned short u16;
typedef short bf16x8 __attribute__((ext_vector_type(8)));
typedef float f32x4 __attribute__((ext_vector_type(4)));

// round-to-nearest-even bf16 split: v ~= hi + lo
__device__ inline void bsplit(float v, u16& h, u16& l) {
    unsigned u = __builtin_bit_cast(unsigned, v);
    unsigned hb = (u + 0x7fffu + ((u >> 16) & 1u)) >> 16;
    float fh = __builtin_bit_cast(float, hb << 16);
    float r = v - fh;
    unsigned u2 = __builtin_bit_cast(unsigned, r);
    unsigned lb = (u2 + 0x7fffu + ((u2 >> 16) & 1u)) >> 16;
    h = (u16)hb; l = (u16)lb;
}

// ---------------------------------------------------------------- CSR build
__global__ void k_deg(const int* __restrict__ ei, int* __restrict__ deg) {
    int e = blockIdx.x * blockDim.x + threadIdx.x;
    if (e >= NEP) return;
    int d = (e < NE) ? ei[NE + e] : (e - NE);
    atomicAdd(&deg[d], 1);
}

__global__ __launch_bounds__(1024) void k_scan(const int* __restrict__ deg, int* __restrict__ off) {
    __shared__ int tsum[1024];
    const int tid = threadIdx.x;
    const int base = tid * 25;
    int s = 0;
    for (int i = 0; i < 25; ++i) { int g = base + i; if (g < NN) s += deg[g]; }
    tsum[tid] = s;
    __syncthreads();
    for (int o = 1; o < 1024; o <<= 1) {
        int v = (tid >= o) ? tsum[tid - o] : 0;
        __syncthreads();
        tsum[tid] += v;
        __syncthreads();
    }
    int run = tid ? tsum[tid - 1] : 0;
    for (int i = 0; i < 25; ++i) {
        int g = base + i;
        if (g < NN) { off[g] = run; run += deg[g]; }
    }
    if (tid == 1023) off[NN] = tsum[1023];
}

__global__ void k_fill(const int* __restrict__ ei, const int* __restrict__ off,
                       int* __restrict__ fill, int* __restrict__ csrc) {
    int e = blockIdx.x * blockDim.x + threadIdx.x;
    if (e >= NEP) return;
    int s = (e < NE) ? ei[e]      : (e - NE);
    int d = (e < NE) ? ei[NE + e] : (e - NE);
    int pos = off[d] + atomicAdd(&fill[d], 1);
    csrc[pos] = s;
}

__global__ void k_dinv(const int* __restrict__ deg, float* __restrict__ dinv) {
    int n = blockIdx.x * blockDim.x + threadIdx.x;
    if (n >= NN) return;
    int dg = deg[n];
    dinv[n] = dg > 0 ? 1.0f / sqrtf((float)dg) : 0.0f;
}

// ---------------------------------------------------------------- split / transpose-split
__global__ void k_split(const float* __restrict__ src, u16* __restrict__ hi,
                        u16* __restrict__ lo, int M, int Ks, int Kp) {
    int half = Kp >> 1;
    int i = blockIdx.x * blockDim.x + threadIdx.x;
    if (i >= M * half) return;
    int m = i / half, kp = (i - m * half) * 2;
    const float* row = src + (size_t)m * Ks;
    float v0 = 0.f, v1 = 0.f;
    if (kp + 1 < Ks) { float2 t = *(const float2*)(row + kp); v0 = t.x; v1 = t.y; }
    else if (kp < Ks) v0 = row[kp];
    u16 h0, l0, h1, l1;
    bsplit(v0, h0, l0); bsplit(v1, h1, l1);
    size_t o = (size_t)m * Kp + kp;
    *(unsigned*)(hi + o) = (unsigned)h0 | ((unsigned)h1 << 16);
    *(unsigned*)(lo + o) = (unsigned)l0 | ((unsigned)l1 << 16);
}

// Th/Tl[N][Kp] <- W[K][N] transposed, zero-padded k in [K,Kp)
__global__ __launch_bounds__(256) void k_tsplit(const float* __restrict__ W,
                                                u16* __restrict__ Th, u16* __restrict__ Tl,
                                                int K, int N, int Kp) {
    __shared__ float tile[32][33];
    int n0 = blockIdx.x * 32, k0 = blockIdx.y * 32;
    int tx = threadIdx.x & 31, ty = threadIdx.x >> 5;   // 32x8
#pragma unroll
    for (int r = 0; r < 4; ++r) {
        int k = k0 + ty + r * 8, n = n0 + tx;
        tile[ty + r * 8][tx] = (k < K && n < N) ? W[(size_t)k * N + n] : 0.f;
    }
    __syncthreads();
#pragma unroll
    for (int r = 0; r < 4; ++r) {
        int nl = ty + r * 8, n = n0 + nl, k = k0 + tx;
        if (n < N && k < Kp) {
            u16 h, l;
            bsplit(tile[tx][nl], h, l);
            Th[(size_t)n * Kp + k] = h;
            Tl[(size_t)n * Kp + k] = l;
        }
    }
}

// ---------------------------------------------------------------- split-bf16 MFMA GEMM
// 1D grid over tiles, col-fastest linearization + bijective XCD swizzle (m204):
// HW assigns block b -> XCD b%8; remap so each XCD owns a CONTIGUOUS chunk of tiles,
// making the 7 col-tiles sharing an A row-panel land on the SAME XCD's L2.
__global__ __launch_bounds__(256, 2) void k_mfma_gemm(
    const u16* __restrict__ Ah, const u16* __restrict__ Al,
    const u16* __restrict__ Bh, const u16* __restrict__ Bl,
    const float* __restrict__ bias, float* __restrict__ C,
    int M, int N, int Kp, int ldc, int relu) {
    __shared__ __align__(16) u16 sAh[128][40];
    __shared__ __align__(16) u16 sAl[128][40];
    __shared__ __align__(16) u16 sBh[128][40];
    __shared__ __align__(16) u16 sBl[128][40];
    const int tid = threadIdx.x;
    // bijective XCD swizzle over flattened tiles
    const int nbn = (N + 127) >> 7;
    const int nwg = gridDim.x;
    const int q = nwg >> 3, r = nwg & 7;
    const int xcd = blockIdx.x & 7, bidx = blockIdx.x >> 3;
    const int tile = (xcd < r ? xcd * (q + 1) : r * (q + 1) + (xcd - r) * q) + bidx;
    const int bm = (tile / nbn) * 128, bn = (tile % nbn) * 128;
    const int lane = tid & 63, w = tid >> 6;
    const int wm = (w >> 1) * 64, wn = (w & 1) * 64;
    const int r16 = lane & 15, kb = (lane >> 4) * 8;
    const int srow = tid >> 1, shalf = tid & 1;
    const int arow = bm + srow, brow = bn + srow;
    const size_t aoff = (size_t)arow * Kp + shalf * 16;
    const size_t boff = (size_t)brow * Kp + shalf * 16;
    const int nsteps = (Kp + 31) / 32;

    uint4 pva[2], pvl[2], pvb[2], pwb[2];
    auto gload = [&](int s) {
        int k0 = s * 32;
        int kc = k0 + shalf * 16;
        bool kok = (kc + 16 <= Kp);
        uint4 z = {0, 0, 0, 0};
        pva[0] = pva[1] = pvl[0] = pvl[1] = z;
        pvb[0] = pvb[1] = pwb[0] = pwb[1] = z;
        if (kok && arow < M) {
            const uint4* p = (const uint4*)(Ah + aoff + k0);
            pva[0] = p[0]; pva[1] = p[1];
            const uint4* q2 = (const uint4*)(Al + aoff + k0);
            pvl[0] = q2[0]; pvl[1] = q2[1];
        }
        if (kok && brow < N) {
            const uint4* p = (const uint4*)(Bh + boff + k0);
            pvb[0] = p[0]; pvb[1] = p[1];
            const uint4* q2 = (const uint4*)(Bl + boff + k0);
            pwb[0] = q2[0]; pwb[1] = q2[1];
        }
    };

    f32x4 acc[4][4] = {};
    gload(0);
    for (int s = 0; s < nsteps; ++s) {
        __syncthreads();
        {
            const int kk = shalf * 16;
            *(uint4*)&sAh[srow][kk] = pva[0]; *(uint4*)&sAh[srow][kk + 8] = pva[1];
            *(uint4*)&sAl[srow][kk] = pvl[0]; *(uint4*)&sAl[srow][kk + 8] = pvl[1];
            *(uint4*)&sBh[srow][kk] = pvb[0]; *(uint4*)&sBh[srow][kk + 8] = pvb[1];
            *(uint4*)&sBl[srow][kk] = pwb[0]; *(uint4*)&sBl[srow][kk + 8] = pwb[1];
        }
        __syncthreads();
        if (s + 1 < nsteps) gload(s + 1);
        bf16x8 fah[4], fal[4], fbh[4], fbl[4];
#pragma unroll
        for (int i = 0; i < 4; ++i) {
            fah[i] = *(const bf16x8*)&sAh[wm + i * 16 + r16][kb];
            fal[i] = *(const bf16x8*)&sAl[wm + i * 16 + r16][kb];
            fbh[i] = *(const bf16x8*)&sBh[wn + i * 16 + r16][kb];
            fbl[i] = *(const bf16x8*)&sBl[wn + i * 16 + r16][kb];
        }
#pragma unroll
        for (int i = 0; i < 4; ++i)
#pragma unroll
            for (int j = 0; j < 4; ++j) {
                acc[i][j] = __builtin_amdgcn_mfma_f32_16x16x32_bf16(fal[i], fbh[j], acc[i][j], 0, 0, 0);
                acc[i][j] = __builtin_amdgcn_mfma_f32_16x16x32_bf16(fah[i], fbl[j], acc[i][j], 0, 0, 0);
                acc[i][j] = __builtin_amdgcn_mfma_f32_16x16x32_bf16(fah[i], fbh[j], acc[i][j], 0, 0, 0);
            }
    }
    const int rbase = (lane >> 4) * 4;
#pragma unroll
    for (int j = 0; j < 4; ++j) {
        int col = bn + wn + j * 16 + r16;
        if (col >= N) continue;
        float bb = bias ? bias[col] : 0.f;
#pragma unroll
        for (int i = 0; i < 4; ++i) {
#pragma unroll
            for (int r2 = 0; r2 < 4; ++r2) {
                int row = bm + wm + i * 16 + rbase + r2;
                if (row < M) {
                    float v = acc[i][j][r2] + bb;
                    if (relu) v = fmaxf(v, 0.f);
                    C[(size_t)row * ldc + col] = v;
                }
            }
        }
    }
}

// ---------------------------------------------------------------- GAT attention
__global__ void k_att(const float* __restrict__ h, const float* __restrict__ wsrc,
                      const float* __restrict__ wdst, float* __restrict__ asrc,
                      float* __restrict__ adst) {
    int node = blockIdx.x * 4 + (threadIdx.x >> 6);
    int lane = threadIdx.x & 63;
    if (node >= NN) return;
    const float* row = h + (size_t)node * HF;
    for (int hh = 0; hh < HEADS; ++hh) {
        float ps = 0.f, pd = 0.f;
        for (int f = lane; f < FXD; f += 64) {
            float v = row[hh * FXD + f];
            ps += v * wsrc[hh * FXD + f];
            pd += v * wdst[hh * FXD + f];
        }
        for (int o = 32; o > 0; o >>= 1) {
            ps += __shfl_down(ps, o);
            pd += __shfl_down(pd, o);
        }
        if (lane == 0) {
            asrc[node * HEADS + hh] = ps;
            adst[node * HEADS + hh] = pd;
        }
    }
}

__global__ void k_mden(const int* __restrict__ off, const int* __restrict__ csrc,
                       const float* __restrict__ asrc, const float* __restrict__ adst,
                       float* __restrict__ mbuf, float* __restrict__ dbuf) {
    int idx = blockIdx.x * blockDim.x + threadIdx.x;
    if (idx >= NN * HEADS) return;
    int d = idx / HEADS, hh = idx % HEADS;
    int s0 = off[d], s1 = off[d + 1];
    float ad = adst[idx];
    float m = -1e30f;
    for (int p = s0; p < s1; ++p) {
        float v = asrc[csrc[p] * HEADS + hh] + ad;
        v = v > 0.f ? v : 0.2f * v;
        m = fmaxf(m, v);
    }
    float den = 0.f;
    for (int p = s0; p < s1; ++p) {
        float v = asrc[csrc[p] * HEADS + hh] + ad;
        v = v > 0.f ? v : 0.2f * v;
        den += expf(v - m);
    }
    mbuf[idx] = m;
    dbuf[idx] = den;
}

// block per dst node: alpha inline, float4 feature MACs
__global__ __launch_bounds__(256) void k_gat_feat(
    const int* __restrict__ off, const int* __restrict__ csrc,
    const float* __restrict__ asrc, const float* __restrict__ adst,
    const float* __restrict__ mbuf, const float* __restrict__ dbuf,
    const float* __restrict__ h, const float* __restrict__ gat_b,
    float* __restrict__ x1) {
    __shared__ float lal[64 * HEADS];
    __shared__ int lsrc[64];
    __shared__ float s_ad[HEADS], s_m[HEADS], s_rd[HEADS];
    const int d = blockIdx.x, tid = threadIdx.x;
    if (tid < HEADS) {
        s_ad[tid] = adst[d * HEADS + tid];
        s_m[tid]  = mbuf[d * HEADS + tid];
        s_rd[tid] = 1.0f / (dbuf[d * HEADS + tid] + 1e-16f);
    }
    const int s0 = off[d], s1 = off[d + 1];
    int hj[4];
#pragma unroll
    for (int j = 0; j < 4; ++j) hj[j] = (tid < 195) ? (tid * 4 + j) / FXD : 0;
    float4 acc = {0.f, 0.f, 0.f, 0.f};
    for (int c0 = s0; c0 < s1; c0 += 64) {
        int cs = min(64, s1 - c0);
        __syncthreads();
        for (int i = tid; i < cs; i += 256) lsrc[i] = csrc[c0 + i];
        __syncthreads();
        for (int i = tid; i < cs * HEADS; i += 256) {
            int e = i / HEADS, hh = i - e * HEADS;
            float v = asrc[lsrc[e] * HEADS + hh] + s_ad[hh];
            v = v > 0.f ? v : 0.2f * v;
            lal[i] = __expf(v - s_m[hh]) * s_rd[hh];
        }
        __syncthreads();
        if (tid < 195) {
            for (int e = 0; e < cs; ++e) {
                const float4 hv = reinterpret_cast<const float4*>(h + (size_t)lsrc[e] * HF)[tid];
                const float* wv = &lal[e * HEADS];
                acc.x += wv[hj[0]] * hv.x;
                acc.y += wv[hj[1]] * hv.y;
                acc.z += wv[hj[2]] * hv.z;
                acc.w += wv[hj[3]] * hv.w;
            }
        }
    }
    if (tid < 195) {
        float4 b = reinterpret_cast<const float4*>(gat_b)[tid];
        float4 o;
        o.x = fmaxf(acc.x + b.x, 0.f);
        o.y = fmaxf(acc.y + b.y, 0.f);
        o.z = fmaxf(acc.z + b.z, 0.f);
        o.w = fmaxf(acc.w + b.w, 0.f);
        reinterpret_cast<float4*>(x1 + (size_t)d * HF)[tid] = o;
    }
}

// block per dst node: y = sum_e dinv[s]*dinv[d]*x1[s,:], bf16-split inline
__global__ __launch_bounds__(256) void k_gcn_agg(
    const int* __restrict__ off, const int* __restrict__ csrc,
    const float* __restrict__ dinv, const float* __restrict__ x1,
    u16* __restrict__ yAh, u16* __restrict__ yAl) {
    __shared__ float lno[256];
    __shared__ int lsrc[256];
    const int d = blockIdx.x, tid = threadIdx.x;
    const int s0 = off[d], s1 = off[d + 1];
    const float dd = dinv[d];
    float4 acc = {0.f, 0.f, 0.f, 0.f};
    for (int c0 = s0; c0 < s1; c0 += 256) {
        int cs = min(256, s1 - c0);
        __syncthreads();
        for (int i = tid; i < cs; i += 256) {
            int s = csrc[c0 + i];
            lsrc[i] = s;
            lno[i] = dinv[s] * dd;
        }
        __syncthreads();
        if (tid < 195) {
            for (int e = 0; e < cs; ++e) {
                const float4 v = reinterpret_cast<const float4*>(x1 + (size_t)lsrc[e] * HF)[tid];
                float wv = lno[e];
                acc.x += wv * v.x; acc.y += wv * v.y; acc.z += wv * v.z; acc.w += wv * v.w;
            }
        }
    }
    if (tid < 195) {
        ushort4 hv, lv;
        bsplit(acc.x, hv.x, lv.x); bsplit(acc.y, hv.y, lv.y);
        bsplit(acc.z, hv.z, lv.z); bsplit(acc.w, hv.w, lv.w);
        *reinterpret_cast<ushort4*>(yAh + (size_t)d * KP_GCN + tid * 4) = hv;
        *reinterpret_cast<ushort4*>(yAl + (size_t)d * KP_GCN + tid * 4) = lv;
    } else if (tid == 195) {
        ushort4 z = {0, 0, 0, 0};
        *reinterpret_cast<ushort4*>(yAh + (size_t)d * KP_GCN + 780) = z;
        *reinterpret_cast<ushort4*>(yAl + (size_t)d * KP_GCN + 780) = z;
    }
}

// ---------------------------------------------------------------- pooling
__global__ void k_gstart(const int* __restrict__ batch, int* __restrict__ gstart) {
    int g = blockIdx.x * blockDim.x + threadIdx.x;
    if (g > NG) return;
    int lo = 0, hi = NN;
    while (lo < hi) {
        int mid = (lo + hi) >> 1;
        if (batch[mid] < g) lo = mid + 1; else hi = mid;
    }
    gstart[g] = lo;
}

__global__ __launch_bounds__(256) void k_pool(const int* __restrict__ gstart,
                                              const float* __restrict__ x2,
                                              float* __restrict__ pool) {
    const int g = blockIdx.x, tid = threadIdx.x;
    const int s0 = gstart[g], s1 = gstart[g + 1];
    if (tid >= 195) return;
    float4 mx = {0.f, 0.f, 0.f, 0.f};
    float4 sm = {0.f, 0.f, 0.f, 0.f};
    for (int n = s0; n < s1; ++n) {
        float4 v = reinterpret_cast<const float4*>(x2 + (size_t)n * HF)[tid];
        sm.x += v.x; sm.y += v.y; sm.z += v.z; sm.w += v.w;
        mx.x = fmaxf(mx.x, v.x); mx.y = fmaxf(mx.y, v.y);
        mx.z = fmaxf(mx.z, v.z); mx.w = fmaxf(mx.w, v.w);
    }
    float inv = 1.0f / (float)max(s1 - s0, 1);
    sm.x *= inv; sm.y *= inv; sm.z *= inv; sm.w *= inv;
    reinterpret_cast<float4*>(pool + (size_t)g * (2 * HF))[tid] = mx;
    reinterpret_cast<float4*>(pool + (size_t)g * (2 * HF) + HF)[tid] = sm;
}

// ---------------------------------------------------------------- split-K head GEMMs
__global__ __launch_bounds__(256) void k_gemm_sk(
    const float* __restrict__ A, const float* __restrict__ B,
    float* __restrict__ P, int M, int N, int K, int KS) {
    __shared__ __align__(16) float As[16][64];
    __shared__ __align__(16) float Bs[16][64];
    const int bm = blockIdx.x * 64, bn = blockIdx.y * 64;
    const int s = blockIdx.z;
    const int k0 = s * KS, k1 = min(k0 + KS, K);
    const int tid = threadIdx.x;
    const int tx = tid & 15, ty = tid >> 4;
    const int arow = tid >> 2, akq = (tid & 3) * 4;
    const int bkk = tid >> 4, bc4 = (tid & 15) * 4;
    float acc[4][4] = {};
    for (int kt = k0; kt < k1; kt += 16) {
        __syncthreads();
        {
            int gk = kt + akq;
            float4 v = {0.f, 0.f, 0.f, 0.f};
            if (gk + 4 <= k1) v = *reinterpret_cast<const float4*>(&A[(size_t)(bm + arow) * K + gk]);
            As[akq + 0][arow] = v.x; As[akq + 1][arow] = v.y;
            As[akq + 2][arow] = v.z; As[akq + 3][arow] = v.w;
            int kk = kt + bkk;
            float4 wv = {0.f, 0.f, 0.f, 0.f};
            if (kk < k1) wv = *reinterpret_cast<const float4*>(&B[(size_t)kk * N + bn + bc4]);
            *reinterpret_cast<float4*>(&Bs[bkk][bc4]) = wv;
        }
        __syncthreads();
#pragma unroll
        for (int kk = 0; kk < 16; ++kk) {
            float4 a = *reinterpret_cast<const float4*>(&As[kk][ty * 4]);
            float4 b = *reinterpret_cast<const float4*>(&Bs[kk][tx * 4]);
            float av[4] = {a.x, a.y, a.z, a.w};
            float bv[4] = {b.x, b.y, b.z, b.w};
#pragma unroll
            for (int i = 0; i < 4; ++i)
#pragma unroll
                for (int j = 0; j < 4; ++j) acc[i][j] += av[i] * bv[j];
        }
    }
    float* Pr = P + (size_t)s * M * N;
#pragma unroll
    for (int i = 0; i < 4; ++i) {
        int row = bm + ty * 4 + i;
        float4 v = {acc[i][0], acc[i][1], acc[i][2], acc[i][3]};
        *reinterpret_cast<float4*>(&Pr[(size_t)row * N + bn + tx * 4]) = v;
    }
}

__global__ void k_reduce(const float* __restrict__ P, const float* __restrict__ bias,
                         float* __restrict__ C, int M, int N, int S, int ldc, int relu) {
    int i = blockIdx.x * blockDim.x + threadIdx.x;
    int nq = N >> 2;
    if (i >= M * nq) return;
    int m = i / nq, c4 = (i - m * nq) * 4;
    const float4* p = reinterpret_cast<const float4*>(P) + i;
    size_t stride4 = (size_t)M * nq;
    float4 a = p[0];
    for (int s = 1; s < S; ++s) {
        float4 v = p[(size_t)s * stride4];
        a.x += v.x; a.y += v.y; a.z += v.z; a.w += v.w;
    }
    float4 b = *reinterpret_cast<const float4*>(bias + c4);
    a.x += b.x; a.y += b.y; a.z += b.z; a.w += b.w;
    if (relu) {
        a.x = fmaxf(a.x, 0.f); a.y = fmaxf(a.y, 0.f);
        a.z = fmaxf(a.z, 0.f); a.w = fmaxf(a.w, 0.f);
    }
    *reinterpret_cast<float4*>(&C[(size_t)m * ldc + c4]) = a;
}

__global__ void k_gemv_out(const float* __restrict__ A, const float* __restrict__ w,
                           const float* __restrict__ b, float* __restrict__ out) {
    int m = blockIdx.x * 4 + (threadIdx.x >> 6);
    int lane = threadIdx.x & 63;
    if (m >= NG) return;
    const float* row = A + (size_t)m * 512;
    float p = 0.f;
#pragma unroll
    for (int t = 0; t < 8; ++t) p += row[lane + t * 64] * w[lane + t * 64];
    for (int o = 32; o > 0; o >>= 1) p += __shfl_down(p, o);
    if (lane == 0) out[m] = p + b[0];
}

// ---------------------------------------------------------------- conv branch
__global__ void k_bmat(const float* __restrict__ emb, float* __restrict__ Bm) {
    int b = blockIdx.x;          // 0..207
    int p = threadIdx.x;
    if (p >= CONVO) return;
    int v = b >> 3, k = b & 7;
    Bm[b * CONVO + p] = emb[v * EMBD + p + k];
}

__global__ __launch_bounds__(256) void k_Amat(const int* __restrict__ target,
                                              const float* __restrict__ convW,
                                              float* __restrict__ Am) {
    __shared__ int vcnt[VOCAB];
    __shared__ int vfill[VOCAB];
    __shared__ int voff[VOCAB + 1];
    __shared__ int vpos[SEQ];
    const int g = blockIdx.x, tid = threadIdx.x;
    if (tid < VOCAB) { vcnt[tid] = 0; vfill[tid] = 0; }
    __syncthreads();
    const int* tg = target + (size_t)g * SEQ;
    for (int s = tid; s < SEQ; s += 256) atomicAdd(&vcnt[tg[s]], 1);
    __syncthreads();
    if (tid == 0) {
        int r = 0;
        for (int v = 0; v < VOCAB; ++v) { voff[v] = r; r += vcnt[v]; }
        voff[VOCAB] = r;
    }
    __syncthreads();
    for (int s = tid; s < SEQ; s += 256) {
        int v = tg[s];
        vpos[voff[v] + atomicAdd(&vfill[v], 1)] = s;
    }
    __syncthreads();
    const int o = tid >> 3, k = tid & 7;
    const float* wrow = convW + (size_t)o * (SEQ * KCONV) + k;
    float* arow = Am + (size_t)g * AROW + o * VK + k;
    for (int v = 0; v < VOCAB; ++v) {
        float r = 0.f;
        int p1 = voff[v + 1];
        for (int p = voff[v]; p < p1; ++p) r += wrow[(size_t)vpos[p] * KCONV];
        arow[v * KCONV] = r;
    }
}

__global__ __launch_bounds__(128) void k_conv(const float* __restrict__ Am,
                                              const float* __restrict__ Bm,
                                              const float* __restrict__ convb,
                                              float* __restrict__ out) {
    __shared__ float As[AROW];
    const int g = blockIdx.x, tid = threadIdx.x;
    for (int i = tid; i < AROW; i += 128) As[i] = Am[(size_t)g * AROW + i];
    __syncthreads();
    if (tid >= CONVO) return;
    const int p = tid;
    float acc[NFILT] = {};
    for (int vk = 0; vk < VK; ++vk) {
        float b = Bm[vk * CONVO + p];
#pragma unroll
        for (int o = 0; o < NFILT; ++o) acc[o] += As[o * VK + vk] * b;
    }
#pragma unroll
    for (int o = 0; o < NFILT; ++o)
        out[(size_t)g * (NFILT * CONVO) + o * CONVO + p] = acc[o] + convb[o];
}

// ---------------------------------------------------------------- launch
extern "C" void kernel_launch(void* const* d_in, const int* in_sizes, int n_in,
                              void* d_out, int out_size, void* d_ws, size_t ws_size,
                              hipStream_t stream) {
    const float* x        = (const float*)d_in[0];
    const int*   ei       = (const int*)d_in[1];
    const int*   batch    = (const int*)d_in[2];
    const int*   target   = (const int*)d_in[3];
    const float* gat_W    = (const float*)d_in[4];
    const float* gat_as   = (const float*)d_in[5];
    const float* gat_ad   = (const float*)d_in[6];
    const float* gat_b    = (const float*)d_in[7];
    const float* gcn_W    = (const float*)d_in[8];
    const float* gcn_b    = (const float*)d_in[9];
    const float* fcg1_W   = (const float*)d_in[10];
    const float* fcg1_b   = (const float*)d_in[11];
    const float* fcg2_W   = (const float*)d_in[12];
    const float* fcg2_b   = (const float*)d_in[13];
    const float* emb      = (const float*)d_in[14];
    const float* conv_W   = (const float*)d_in[15];
    const float* conv_b   = (const float*)d_in[16];
    const float* fcxt_W   = (const float*)d_in[17];
    const float* fcxt_b   = (const float*)d_in[18];
    const float* fc1_W    = (const float*)d_in[19];
    const float* fc1_b    = (const float*)d_in[20];
    const float* fc2_W    = (const float*)d_in[21];
    const float* fc2_b    = (const float*)d_in[22];
    const float* out_W    = (const float*)d_in[23];
    const float* out_b    = (const float*)d_in[24];
    float* outp = (float*)d_out;

    // ---- workspace layout (float units) ----
    // R1: h -> {yAh,yAl} -> small arena.     R2: x1 -> x2.
    const size_t R1SZ = 19600000, R2SZ = 19600000;
    float* R1   = (float*)d_ws;
    float* R2   = R1 + R1SZ;
    float* xAf  = R2 + R2SZ;                          // 2,000,000 (xAh+xAl)
    float* gWf  = xAf + 2000000;                      // 64,000
    float* cWf  = gWf + 64000;                        // 612,000 (cWh+cWl)
    float* asrc = cWf + 612000;
    float* adst = asrc + (size_t)NN * HEADS;
    float* mbuf = adst + (size_t)NN * HEADS;
    float* dbuf = mbuf + (size_t)NN * HEADS;
    float* dinv = dbuf + (size_t)NN * HEADS;
    int* deg      = (int*)(dinv + NN);
    int* csr_off  = deg + NN;
    int* csr_fill = csr_off + (NN + 1);
    int* csr_src  = csr_fill + NN;
    int* gstart   = csr_src + NEP;

    u16* xAh = (u16*)xAf;             u16* xAl = xAh + (size_t)NN * KP_GAT;
    u16* gWh = (u16*)gWf;             u16* gWl = gWh + (size_t)HF * KP_GAT;
    u16* cWh = (u16*)cWf;             u16* cWl = cWh + (size_t)HF * KP_GCN;

    hipMemsetAsync(deg, 0, NN * sizeof(int), stream);
    hipMemsetAsync(csr_fill, 0, NN * sizeof(int), stream);

    const int NTILES = ((NN + 127) / 128) * ((HF + 127) / 128);   // 196*7 = 1372

    // ---- GAT: h = x @ gat_W via split-bf16 MFMA ----
    k_split<<<(NN * (KP_GAT / 2) + 255) / 256, 256, 0, stream>>>(x, xAh, xAl, NN, FXD, KP_GAT);
    k_tsplit<<<dim3((HF + 31) / 32, (KP_GAT + 31) / 32), 256, 0, stream>>>(
        gat_W, gWh, gWl, FXD, HF, KP_GAT);
    k_tsplit<<<dim3((HF + 31) / 32, (KP_GCN + 31) / 32), 256, 0, stream>>>(
        gcn_W, cWh, cWl, HF, HF, KP_GCN);
    k_mfma_gemm<<<NTILES, 256, 0, stream>>>(
        xAh, xAl, gWh, gWl, nullptr, R1, NN, HF, KP_GAT, HF, 0);        // h -> R1

    k_att<<<(NN + 3) / 4, 256, 0, stream>>>(R1, gat_as, gat_ad, asrc, adst);
    k_deg<<<(NEP + 255) / 256, 256, 0, stream>>>(ei, deg);
    k_scan<<<1, 1024, 0, stream>>>(deg, csr_off);
    k_fill<<<(NEP + 255) / 256, 256, 0, stream>>>(ei, csr_off, csr_fill, csr_src);
    k_dinv<<<(NN + 255) / 256, 256, 0, stream>>>(deg, dinv);
    k_mden<<<(NN * HEADS + 255) / 256, 256, 0, stream>>>(csr_off, csr_src, asrc, adst, mbuf, dbuf);
    k_gat_feat<<<NN, 256, 0, stream>>>(csr_off, csr_src, asrc, adst, mbuf, dbuf,
                                       R1, gat_b, R2);                  // x1 -> R2 (h in R1 dead)

    // ---- GCN: aggregate + inline bf16-split (x1 in R2 -> yA in R1), then MFMA ----
    k_gcn_agg<<<NN, 256, 0, stream>>>(csr_off, csr_src, dinv, R2, (u16*)R1,
                                      (u16*)R1 + (size_t)NN * KP_GCN);
    k_mfma_gemm<<<NTILES, 256, 0, stream>>>(
        (u16*)R1, (u16*)R1 + (size_t)NN * KP_GCN, cWh, cWl, gcn_b, R2,
        NN, HF, KP_GCN, HF, 1);                                         // x2 -> R2 (x1 dead)

    // ---- pooling + graph MLP (arena in R1; yA dead after GCN GEMM) ----
    float* poolR = R1;
    float* xg1R  = poolR + (size_t)NG * 2 * HF;
    float* xcR   = xg1R + (size_t)NG * 1024;
    float* f1R   = xcR + (size_t)NG * 256;
    float* f2R   = f1R + (size_t)NG * 1024;
    float* AmatR = f2R + (size_t)NG * 512;
    float* BmatR = AmatR + (size_t)NG * AROW;
    float* convR = BmatR + (size_t)VK * CONVO;
    float* partR = convR + (size_t)NG * NFILT * CONVO;

    k_gstart<<<1, 1024, 0, stream>>>(batch, gstart);
    k_pool<<<NG, 256, 0, stream>>>(gstart, R2, poolR);
    k_gemm_sk<<<dim3(8, 16, 8), 256, 0, stream>>>(poolR, fcg1_W, partR, NG, 1024, 1560, 208);
    k_reduce<<<512, 256, 0, stream>>>(partR, fcg1_b, xg1R, NG, 1024, 8, 1024, 1);
    k_gemm_sk<<<dim3(8, 2, 16), 256, 0, stream>>>(xg1R, fcg2_W, partR, NG, 128, 1024, 64);
    k_reduce<<<64, 256, 0, stream>>>(partR, fcg2_b, xcR, NG, 128, 16, 256, 0);

    // ---- target CNN branch (vocab-factorized conv) ----
    k_bmat<<<VK, 128, 0, stream>>>(emb, BmatR);
    k_Amat<<<NG, 256, 0, stream>>>(target, conv_W, AmatR);
    k_conv<<<NG, 128, 0, stream>>>(AmatR, BmatR, conv_b, convR);
    k_gemm_sk<<<dim3(8, 2, 16), 256, 0, stream>>>(convR, fcxt_W, partR, NG, 128, 3872, 256);
    k_reduce<<<64, 256, 0, stream>>>(partR, fcxt_b, xcR + 128, NG, 128, 16, 256, 0);

    // ---- fusion head ----
    k_gemm_sk<<<dim3(8, 16, 4), 256, 0, stream>>>(xcR, fc1_W, partR, NG, 1024, 256, 64);
    k_reduce<<<512, 256, 0, stream>>>(partR, fc1_b, f1R, NG, 1024, 4, 1024, 1);
    k_gemm_sk<<<dim3(8, 8, 8), 256, 0, stream>>>(f1R, fc2_W, partR, NG, 512, 1024, 128);
    k_reduce<<<256, 256, 0, stream>>>(partR, fc2_b, f2R, NG, 512, 8, 512, 1);
    k_gemv_out<<<128, 256, 0, stream>>>(f2R, out_W, out_b, outp);
}